// Round 7
// baseline (95.507 us; speedup 1.0000x reference)
//
#include <hip/hip_runtime.h>

#define NN   2048
#define DD   64
#define QB   64      // Q rows per block (32 per wave, 2 waves)
#define KVB  64      // KV rows per iteration
#define NT   (NN / KVB)
#define BH   32      // B*H
#define BHND (BH * NN * DD)
#define SC   0.18033688f     // 0.125 * log2(e): softmax in exp2 domain
#define THR  11.5415603f     // 8 * log2(e): defer-max threshold

typedef float    f32x4  __attribute__((ext_vector_type(4)));
typedef short    bf16x8 __attribute__((ext_vector_type(8)));
typedef short    bf16x4 __attribute__((ext_vector_type(4)));
typedef unsigned u32x4  __attribute__((ext_vector_type(4)));

#define WAIT_VM8()   asm volatile("s_waitcnt vmcnt(8)" ::: "memory")
#define WAIT_VM0()   asm volatile("s_waitcnt vmcnt(0)" ::: "memory")
#define WAIT_LGKM0() asm volatile("s_waitcnt lgkmcnt(0)" ::: "memory")
#define SBAR()       __builtin_amdgcn_s_barrier()
#define SFENCE()     __builtin_amdgcn_sched_barrier(0)

__device__ __forceinline__ short f2bf(float x){
    unsigned u = __float_as_uint(x);
    u += 0x7FFF + ((u >> 16) & 1);      // round-to-nearest-even
    return (short)(u >> 16);
}

__device__ __forceinline__ unsigned cvt_pk(float lo, float hi){
    unsigned r;
    asm("v_cvt_pk_bf16_f32 %0, %1, %2" : "=v"(r) : "v"(lo), "v"(hi));
    return r;
}

__device__ __forceinline__ float exp2_fast(float x){
    float r;
    asm("v_exp_f32 %0, %1" : "=v"(r) : "v"(x));
    return r;
}

__device__ __forceinline__ float max3f(float a, float b, float c){
    return fmaxf(fmaxf(a, b), c);       // clang fuses to v_max3_f32
}

__device__ __forceinline__ void gload_lds16(const short* g, short* l) {
    __builtin_amdgcn_global_load_lds(
        (const __attribute__((address_space(1))) void*)g,
        (__attribute__((address_space(3))) void*)l, 16, 0, 0);
}

// ---------------- merged pre-pass ----------------
// z=0: K fp32 -> bf16.  z=1 (x<32): V [N][D] fp32 -> Vt [D][N] bf16, sigma-permuted.
__global__ __launch_bounds__(256)
void prep(const float* __restrict__ k, const float* __restrict__ v,
          short* __restrict__ kws, short* __restrict__ vtws)
{
    const int tid = threadIdx.x;
    if (blockIdx.z == 0) {
        long i = (((long)blockIdx.y * 64 + blockIdx.x) * 256 + tid) * 8;
        f32x4 x0 = *(const f32x4*)(k + i);
        f32x4 x1 = *(const f32x4*)(k + i + 4);
        bf16x8 o;
        #pragma unroll
        for (int j = 0; j < 4; ++j) { o[j] = f2bf(x0[j]); o[4 + j] = f2bf(x1[j]); }
        *(bf16x8*)(kws + i) = o;
        return;
    }
    if (blockIdx.x >= 32) return;
    const int bh = blockIdx.y;
    const int n0 = blockIdx.x * 64;
    __shared__ __align__(16) short tile[64][72];

    const float* vb = v + (long)bh * NN * DD;
    const int nl = tid >> 4;
    const int d0 = (tid & 15) * 4;
    #pragma unroll
    for (int pass = 0; pass < 4; ++pass) {
        int n = nl + pass * 16;
        f32x4 x = *(const f32x4*)(vb + (long)(n0 + n) * DD + d0);
        #pragma unroll
        for (int j = 0; j < 4; ++j) tile[d0 + j][n] = f2bf(x[j]);
    }
    __syncthreads();
    short* vtb = vtws + (long)bh * DD * NN;
    const int nc  = (tid & 7) * 8;
    const int kk  = nc >> 5;
    const int lgc = (nc >> 3) & 3;
    #pragma unroll
    for (int itr = 0; itr < 2; ++itr) {
        int d = (tid >> 3) + itr * 32;
        bf16x4 lo = *(const bf16x4*)&tile[d][kk * 32 + lgc * 4];
        bf16x4 hi = *(const bf16x4*)&tile[d][kk * 32 + 16 + lgc * 4];
        bf16x8 r;
        #pragma unroll
        for (int j = 0; j < 4; ++j) { r[j] = lo[j]; r[4 + j] = hi[j]; }
        *(bf16x8*)(vtb + (long)d * NN + n0 + nc) = r;
    }
}

// ---------------- main fused attention v7: KV-split flash-decode ----------------
// NSPLIT=2: each block does NN/2 of the KV axis (16 sequential tiles),
// writes unnormalized O + (m,l); combine pass merges. NSPLIT=1: v6 behavior.
template<int NSPLIT>
__global__ __launch_bounds__(128)
void attn_fwd_v7(const float* __restrict__ q,
                 const short* __restrict__ kws,
                 const short* __restrict__ vtws,
                 float* __restrict__ o0,        // d_out: split 0 (or final if NSPLIT==1)
                 float* __restrict__ o1,        // ws: split 1 partial
                 float2* __restrict__ ml)       // ws: [split][bh][n] (m, l)
{
    // bijective XCD swizzle: all blocks of one bh land on one XCD
    const int l     = blockIdx.x;
    const int xcd   = l & 7;
    const int idx   = l >> 3;
    const int qtile = idx & 31;
    const int rest  = idx >> 5;
    const int split = (NSPLIT == 2) ? (rest & 1) : 0;
    const int bh    = xcd + 8 * ((NSPLIT == 2) ? (rest >> 1) : rest);

    const int tid   = threadIdx.x;       // 0..127
    const int wave  = tid >> 6;          // 0..1
    const int lane  = tid & 63;
    const int l16   = lane & 15;
    const int lg    = lane >> 4;
    const int l7    = l16 & 7;

    const int kvbase = split * (NN / NSPLIT);
    const int ntile  = NN / NSPLIT / KVB;

    __shared__ __align__(16) short k_lds[2][KVB * DD];   // 16 KB
    __shared__ __align__(16) short v_lds[2][DD * KVB];   // 16 KB

    const long base  = (long)bh * NN * DD;
    const int  qrow0 = qtile * QB + wave * 32;

    // ---- load Q (2 sub-blocks of 16 rows), convert with scale SC ----
    bf16x8 aq[2][2];
    #pragma unroll
    for (int j = 0; j < 2; ++j) {
        const float* qp = q + base + (long)(qrow0 + j * 16 + l16) * DD + lg * 8;
        #pragma unroll
        for (int c = 0; c < 2; ++c) {
            f32x4 x0 = *(const f32x4*)(qp + c * 32);
            f32x4 x1 = *(const f32x4*)(qp + c * 32 + 4);
            u32x4 pk;
            pk[0] = cvt_pk(x0[0] * SC, x0[1] * SC);
            pk[1] = cvt_pk(x0[2] * SC, x0[3] * SC);
            pk[2] = cvt_pk(x1[0] * SC, x1[1] * SC);
            pk[3] = cvt_pk(x1[2] * SC, x1[3] * SC);
            aq[j][c] = __builtin_bit_cast(bf16x8, pk);
        }
    }

    const int srow = lane >> 3;
    const int scol = 8 * ((lane & 7) ^ srow);
    const short* kg = kws  + base;
    const short* vg = vtws + (long)bh * DD * NN;

    auto stage = [&](int buf, int kv0) {
        #pragma unroll
        for (int j = 0; j < 4; ++j) {
            int b8 = wave * 32 + j * 8;
            gload_lds16(kg + (long)(kv0 + b8 + srow) * DD + scol, &k_lds[buf][b8 * DD]);
        }
        #pragma unroll
        for (int j = 0; j < 4; ++j) {
            int b8 = wave * 32 + j * 8;
            gload_lds16(vg + (long)(b8 + srow) * NN + kv0 + scol, &v_lds[buf][b8 * KVB]);
        }
    };

    float mrun[2] = {-1e30f, -1e30f}, lrun[2] = {0.f, 0.f};
    f32x4 acc[4][2];
    #pragma unroll
    for (int t = 0; t < 4; ++t)
        #pragma unroll
        for (int j = 0; j < 2; ++j) acc[t][j] = f32x4{0.f, 0.f, 0.f, 0.f};

    int cur = 0;
    stage(0, kvbase);
    stage(1, kvbase + KVB);

    for (int t = 0; t < ntile; ++t) {
        if (t == ntile - 1) { WAIT_VM0(); } else { WAIT_VM8(); }
        SBAR(); SFENCE();

        const short* kbuf = k_lds[cur];
        const short* vbuf = v_lds[cur];

        // ---- swapped QK^T: s[cb][j][r] = S[q = j*16+l16][kv = cb*16+lg*4+r] ----
        f32x4 s[4][2];
        __builtin_amdgcn_s_setprio(1);
        #pragma unroll
        for (int cb = 0; cb < 4; ++cb) {
            bf16x8 ka0 = *(const bf16x8*)&kbuf[(cb * 16 + l16) * DD +
                                               ((lg * 8) ^ (l7 << 3))];
            bf16x8 ka1 = *(const bf16x8*)&kbuf[(cb * 16 + l16) * DD +
                                               ((32 + lg * 8) ^ (l7 << 3))];
            #pragma unroll
            for (int j = 0; j < 2; ++j) {
                f32x4 z = f32x4{0.f, 0.f, 0.f, 0.f};
                z = __builtin_amdgcn_mfma_f32_16x16x32_bf16(ka0, aq[j][0], z, 0, 0, 0);
                z = __builtin_amdgcn_mfma_f32_16x16x32_bf16(ka1, aq[j][1], z, 0, 0, 0);
                s[cb][j] = z;
            }
        }
        __builtin_amdgcn_s_setprio(0);

        // ---- online softmax (exp2 domain), defer-max ----
        float mx[2];
        #pragma unroll
        for (int j = 0; j < 2; ++j) {
            float t0 = max3f(s[0][j][0], s[0][j][1], s[0][j][2]);
            float t1 = max3f(s[0][j][3], s[1][j][0], s[1][j][1]);
            float t2 = max3f(s[1][j][2], s[1][j][3], s[2][j][0]);
            float t3 = max3f(s[2][j][1], s[2][j][2], s[2][j][3]);
            float t4 = max3f(s[3][j][0], s[3][j][1], s[3][j][2]);
            float m  = max3f(max3f(t0, t1, t2), fmaxf(t3, t4), s[3][j][3]);
            m = fmaxf(m, __shfl_xor(m, 16));
            m = fmaxf(m, __shfl_xor(m, 32));
            mx[j] = m;
        }

        bool need = (mx[0] - mrun[0] > THR) || (mx[1] - mrun[1] > THR);
        if (__any(need)) {
            #pragma unroll
            for (int j = 0; j < 2; ++j) {
                float mn    = fmaxf(mrun[j], mx[j]);
                float alpha = exp2_fast(mrun[j] - mn);
                mrun[j] = mn;
                lrun[j] *= alpha;
                #pragma unroll
                for (int r = 0; r < 4; ++r) {
                    float ar = __shfl(alpha, lg * 4 + r);
                    #pragma unroll
                    for (int t2 = 0; t2 < 4; ++t2) acc[t2][j][r] *= ar;
                }
            }
        }

        #pragma unroll
        for (int j = 0; j < 2; ++j) {
            float rs = 0.f;
            #pragma unroll
            for (int cb = 0; cb < 4; ++cb)
                #pragma unroll
                for (int r = 0; r < 4; ++r) {
                    float p = exp2_fast(s[cb][j][r] - mrun[j]);
                    s[cb][j][r] = p;
                    rs += p;
                }
            rs += __shfl_xor(rs, 16);
            rs += __shfl_xor(rs, 32);
            lrun[j] += rs;
        }

        // ---- pack P in-register: pa[j][kk][i] = s[2kk+(i>>2)][j][i&3] ----
        bf16x8 pa[2][2];
        #pragma unroll
        for (int j = 0; j < 2; ++j) {
            u32x4 w0, w1;
            w0[0] = cvt_pk(s[0][j][0], s[0][j][1]);  w0[1] = cvt_pk(s[0][j][2], s[0][j][3]);
            w0[2] = cvt_pk(s[1][j][0], s[1][j][1]);  w0[3] = cvt_pk(s[1][j][2], s[1][j][3]);
            w1[0] = cvt_pk(s[2][j][0], s[2][j][1]);  w1[1] = cvt_pk(s[2][j][2], s[2][j][3]);
            w1[2] = cvt_pk(s[3][j][0], s[3][j][1]);  w1[3] = cvt_pk(s[3][j][2], s[3][j][3]);
            pa[j][0] = __builtin_bit_cast(bf16x8, w0);
            pa[j][1] = __builtin_bit_cast(bf16x8, w1);
        }

        // ---- PV: bv fragments shared across both sub-blocks ----
        __builtin_amdgcn_s_setprio(1);
        #pragma unroll
        for (int t2 = 0; t2 < 4; ++t2) {
            bf16x8 bv0 = *(const bf16x8*)&vbuf[(t2 * 16 + l16) * KVB +
                                               ((lg * 8) ^ (l7 << 3))];
            bf16x8 bv1 = *(const bf16x8*)&vbuf[(t2 * 16 + l16) * KVB +
                                               ((32 + lg * 8) ^ (l7 << 3))];
            #pragma unroll
            for (int j = 0; j < 2; ++j) {
                acc[t2][j] = __builtin_amdgcn_mfma_f32_16x16x32_bf16(pa[j][0], bv0, acc[t2][j], 0, 0, 0);
                acc[t2][j] = __builtin_amdgcn_mfma_f32_16x16x32_bf16(pa[j][1], bv1, acc[t2][j], 0, 0, 0);
            }
        }
        __builtin_amdgcn_s_setprio(0);

        if (t + 2 < ntile) {
            SFENCE();
            WAIT_LGKM0();
            SBAR(); SFENCE();
            stage(cur, kvbase + (t + 2) * KVB);
        }
        cur ^= 1;
    }

    // ---- epilogue ----
    if (NSPLIT == 1) {
        float* op = o0 + base + (long)qrow0 * DD;
        #pragma unroll
        for (int j = 0; j < 2; ++j) {
            float inv = 1.f / lrun[j];
            #pragma unroll
            for (int r = 0; r < 4; ++r) {
                float ir = __shfl(inv, lg * 4 + r);
                #pragma unroll
                for (int t2 = 0; t2 < 4; ++t2)
                    op[(long)(j * 16 + lg * 4 + r) * DD + t2 * 16 + l16] = acc[t2][j][r] * ir;
            }
        }
    } else {
        float* op = (split == 0 ? o0 : o1) + base + (long)qrow0 * DD;
        #pragma unroll
        for (int j = 0; j < 2; ++j) {
            #pragma unroll
            for (int r = 0; r < 4; ++r)
                #pragma unroll
                for (int t2 = 0; t2 < 4; ++t2)
                    op[(long)(j * 16 + lg * 4 + r) * DD + t2 * 16 + l16] = acc[t2][j][r];
        }
        if (lg == 0) {
            #pragma unroll
            for (int j = 0; j < 2; ++j)
                ml[(long)split * BH * NN + (long)bh * NN + qrow0 + j * 16 + l16] =
                    float2{mrun[j], lrun[j]};
        }
    }
}

// ---------------- combine: out = (w0*o0 + w1*o1) / (w0*l0 + w1*l1) ----------------
__global__ __launch_bounds__(256)
void combine(float* __restrict__ out, const float* __restrict__ o1,
             const float2* __restrict__ ml)
{
    int gid = blockIdx.x * 256 + threadIdx.x;    // 0 .. BHND/4-1
    int row = gid >> 4;                          // bh*NN + q
    int c   = (gid & 15) * 4;
    float2 a = ml[row];                          // split 0
    float2 b = ml[BH * NN + row];                // split 1
    float m  = fmaxf(a.x, b.x);
    float w0 = exp2_fast(a.x - m);
    float w1 = exp2_fast(b.x - m);
    float inv = 1.f / (w0 * a.y + w1 * b.y);
    long off = (long)row * DD + c;
    f32x4 x0 = *(const f32x4*)(out + off);
    f32x4 x1 = *(const f32x4*)(o1 + off);
    f32x4 r;
    #pragma unroll
    for (int j = 0; j < 4; ++j) r[j] = (w0 * x0[j] + w1 * x1[j]) * inv;
    *(f32x4*)(out + off) = r;
}

extern "C" void kernel_launch(void* const* d_in, const int* in_sizes, int n_in,
                              void* d_out, int out_size, void* d_ws, size_t ws_size,
                              hipStream_t stream) {
    const float* q = (const float*)d_in[0];
    const float* k = (const float*)d_in[1];
    const float* v = (const float*)d_in[2];
    float* out = (float*)d_out;

    short*  kws  = (short*)d_ws;
    short*  vtws = kws + BHND;
    float*  o1   = (float*)(vtws + BHND);
    float2* ml   = (float2*)(o1 + BHND);
    const size_t need = (size_t)2 * BHND * 2 + (size_t)BHND * 4 + (size_t)2 * BH * NN * 8;

    prep<<<dim3(64, 32, 2), 256, 0, stream>>>(k, v, kws, vtws);
    if (ws_size >= need) {
        attn_fwd_v7<2><<<2048, 128, 0, stream>>>(q, kws, vtws, out, o1, ml);
        combine<<<BHND / 4 / 256, 256, 0, stream>>>(out, o1, ml);
    } else {
        attn_fwd_v7<1><<<1024, 128, 0, stream>>>(q, kws, vtws, out, nullptr, nullptr);
    }
}